// Round 4
// baseline (781.446 us; speedup 1.0000x reference)
//
#include <hip/hip_runtime.h>
#include <hip/hip_bf16.h>

#define Bb 256
#define Tt 512
#define Ii 256
#define Hh 512
#define Aa 18

typedef __bf16 bf16x8 __attribute__((ext_vector_type(8)));
typedef unsigned short u16x8 __attribute__((ext_vector_type(8)));
typedef unsigned short u16x4 __attribute__((ext_vector_type(4)));
typedef float f32x4 __attribute__((ext_vector_type(4)));
typedef int i32x4 __attribute__((ext_vector_type(4)));
typedef int i32x2 __attribute__((ext_vector_type(2)));

__device__ __forceinline__ unsigned short f2bf(float x) {
    unsigned u = __builtin_bit_cast(unsigned, x);
    u += 0x7FFFu + ((u >> 16) & 1u);   // round-to-nearest-even
    return (unsigned short)(u >> 16);
}
__device__ __forceinline__ float bf2f(unsigned short h) {
    unsigned u = ((unsigned)h) << 16;
    return __builtin_bit_cast(float, u);
}

__device__ __forceinline__ f32x4 mfma_bf16(u16x8 a, u16x8 b, f32x4 c) {
    return __builtin_amdgcn_mfma_f32_16x16x32_bf16(
        __builtin_bit_cast(bf16x8, a), __builtin_bit_cast(bf16x8, b), c, 0, 0, 0);
}
#define MFMA8(a, b, c) __builtin_amdgcn_mfma_i32_16x16x64_i8((a), (b), (c), 0, 0, 0)

__device__ __forceinline__ float tanh_fast(float x) {
    float e = __expf(2.0f * x);
    return 1.0f - 2.0f * __builtin_amdgcn_rcpf(1.0f + e);
}

// lane^32 sum via permlane32_swap (VALU, ~4 cyc) — NOT ds_bpermute (120-cyc LDS)
#if __has_builtin(__builtin_amdgcn_permlane32_swap)
__device__ __forceinline__ int xor32_sum(int s) {
    i32x2 r = __builtin_amdgcn_permlane32_swap(s, s, false, false);
    return r[0] + r[1];
}
#else
__device__ __forceinline__ int xor32_sum(int s) {
    int o = __builtin_amdgcn_ds_bpermute(((threadIdx.x ^ 32) & 63) << 2, s);
    return s + o;
}
#endif

// 127 / (1/sqrt(512)) : quantization scale for W_hh and W_fc (both U(-s,s), s=1/sqrt(512))
#define QW_SCALE 2873.6819587417f

// ---------------- prep kernels ----------------

// bias, W_fc i8 B-fragments (A padded 18->32), lengths tail
__global__ void k_misc(const float* __restrict__ b_ih, const float* __restrict__ b_hh,
                       const float* __restrict__ w_fc, const int* __restrict__ lengths,
                       float* __restrict__ bias, int* __restrict__ wfcfrag,
                       float* __restrict__ out_tail) {
    int tid = threadIdx.x;
    for (int h = tid; h < Hh; h += 256) bias[h] = b_ih[h] + b_hh[h];
    for (int idx = tid; idx < 1024; idx += 256) {
        int nt = idx >> 9, k8 = (idx >> 6) & 7, lane = idx & 63;
        int a = nt * 16 + (lane & 15);
        int kb = k8 * 64 + (lane >> 4) * 16;
        int q[16];
#pragma unroll
        for (int i = 0; i < 16; ++i) {
            int qi = 0;
            if (a < Aa) {
                qi = (int)rintf(w_fc[a * Hh + kb + i] * QW_SCALE);
                qi = min(127, max(-127, qi));
            }
            q[i] = qi & 0xFF;
        }
        i32x4 pk;
#pragma unroll
        for (int d = 0; d < 4; ++d)
            pk[d] = q[d*4] | (q[d*4+1] << 8) | (q[d*4+2] << 16) | (q[d*4+3] << 24);
        *((i32x4*)wfcfrag + idx) = pk;
    }
    if (tid < Bb) out_tail[tid] = (float)lengths[tid];
}

__global__ void k_cast_wih(const float* __restrict__ wih, unsigned short* __restrict__ wih_bf) {
    int idx = (blockIdx.x * 256 + threadIdx.x) * 4;
    float4 f = *(const float4*)(wih + idx);
    u16x4 r = { f2bf(f.x), f2bf(f.y), f2bf(f.z), f2bf(f.w) };
    *(u16x4*)(wih_bf + idx) = r;
}

// W_hh -> (a) i8 MFMA B-fragments (tiles 0-1 consumed), (b) sdot4-packed dwords
// for VALU tiles 2-3: wvalu[((w*2+m)*8 + j)*64 + lane] = 16 i8 of
// W_hh[col = w*64+(m+2)*16+l15][k = ((w+j)&7)*64 + quad*16 .. +16]
// (j-slot pre-permuted to match k_rnn's af[j] register layout)
__global__ void k_prep_whh(const float* __restrict__ whh, int* __restrict__ w1frag,
                           int* __restrict__ wvalu) {
    int idx = blockIdx.x * 256 + threadIdx.x;   // 16384 + 8192 total
    const float* src;
    int* dst;
    if (idx < 16384) {
        int lane = idx & 63, k8 = (idx >> 6) & 7, nt = (idx >> 9) & 3, w = idx >> 11;
        int row = w * 64 + nt * 16 + (lane & 15);
        int kb = k8 * 64 + (lane >> 4) * 16;
        src = whh + row * Hh + kb;
        dst = (int*)((i32x4*)w1frag + idx);
    } else {
        int i2 = idx - 16384;                   // ((w*2+m)*8 + j)*64 + lane
        int lane = i2 & 63, j = (i2 >> 6) & 7;
        int rest = i2 >> 9;                     // w*2 + m
        int m = rest & 1, w = rest >> 1;
        int q = lane >> 4, l15 = lane & 15;
        int col = w * 64 + (m + 2) * 16 + l15;
        int k8p = (w + j) & 7;
        src = whh + col * Hh + k8p * 64 + q * 16;
        dst = (int*)((i32x4*)wvalu + i2);
    }
    int q[16];
#pragma unroll
    for (int i = 0; i < 16; ++i) {
        int qi = (int)rintf(src[i] * QW_SCALE);
        qi = min(127, max(-127, qi));
        q[i] = qi & 0xFF;
    }
    i32x4 pk;
#pragma unroll
    for (int d = 0; d < 4; ++d)
        pk[d] = q[d*4] | (q[d*4+1] << 8) | (q[d*4+2] << 16) | (q[d*4+3] << 24);
    *(i32x4*)dst = pk;
}

__global__ void k_prefill(const float* __restrict__ b_fc, float* __restrict__ out) {
    long long base = ((long long)blockIdx.x * 256 + threadIdx.x) * 4;
    int r = (int)(base % Aa);
    float4 v;
    v.x = b_fc[r]; r = (r == Aa - 1) ? 0 : r + 1;
    v.y = b_fc[r]; r = (r == Aa - 1) ? 0 : r + 1;
    v.z = b_fc[r]; r = (r == Aa - 1) ? 0 : r + 1;
    v.w = b_fc[r];
    *(float4*)(out + base) = v;
}

// ---------------- proj GEMM -> consumer-order layout for k_rnn ----------------

__global__ __launch_bounds__(512, 2) void k_gemm_proj(
        const float* __restrict__ x, const unsigned short* __restrict__ wih_bf,
        const float* __restrict__ bias, const int* __restrict__ lengths,
        unsigned short* __restrict__ projsw) {
    const int mbase = blockIdx.x * 128;
    const int b = mbase >> 9, t0 = mbase & 511;
    if (t0 >= lengths[b]) return;
    __shared__ __align__(16) unsigned short As[128 * 40];
    __shared__ __align__(16) unsigned short Bs[512 * 40];
    const int tid = threadIdx.x;
    const int wave = tid >> 6, lane = tid & 63;
    const int wm = wave & 1, wn = wave >> 1;
    const int quad = lane >> 4, l15 = lane & 15;

    f32x4 acc[4][8];
    const f32x4 zz = {0.f, 0.f, 0.f, 0.f};
#pragma unroll
    for (int i = 0; i < 4; i++)
#pragma unroll
        for (int j = 0; j < 8; j++) acc[i][j] = zz;

    const int arow = tid >> 2, aq = tid & 3;
    const float* aptr = x + (mbase + arow) * Ii + aq * 8;
    const unsigned short* bptr = wih_bf + tid * Ii;

    float4 f0 = *(const float4*)(aptr);
    float4 f1 = *(const float4*)(aptr + 4);
    u16x8 bs0 = *(const u16x8*)(bptr);
    u16x8 bs1 = *(const u16x8*)(bptr + 8);
    u16x8 bs2 = *(const u16x8*)(bptr + 16);
    u16x8 bs3 = *(const u16x8*)(bptr + 24);

    for (int kb = 0; kb < Ii / 32; ++kb) {
        u16x8 a8 = { f2bf(f0.x), f2bf(f0.y), f2bf(f0.z), f2bf(f0.w),
                     f2bf(f1.x), f2bf(f1.y), f2bf(f1.z), f2bf(f1.w) };
        *(u16x8*)&As[arow * 40 + aq * 8] = a8;
        *(u16x8*)&Bs[tid * 40]      = bs0;
        *(u16x8*)&Bs[tid * 40 + 8]  = bs1;
        *(u16x8*)&Bs[tid * 40 + 16] = bs2;
        *(u16x8*)&Bs[tid * 40 + 24] = bs3;
        __syncthreads();
        if (kb < Ii / 32 - 1) {
            f0 = *(const float4*)(aptr + (kb + 1) * 32);
            f1 = *(const float4*)(aptr + (kb + 1) * 32 + 4);
            bs0 = *(const u16x8*)(bptr + (kb + 1) * 32);
            bs1 = *(const u16x8*)(bptr + (kb + 1) * 32 + 8);
            bs2 = *(const u16x8*)(bptr + (kb + 1) * 32 + 16);
            bs3 = *(const u16x8*)(bptr + (kb + 1) * 32 + 24);
        }
        u16x8 af[4], bfr[8];
#pragma unroll
        for (int mt = 0; mt < 4; mt++)
            af[mt] = *(const u16x8*)&As[(wm * 64 + mt * 16 + l15) * 40 + quad * 8];
#pragma unroll
        for (int nt = 0; nt < 8; nt++)
            bfr[nt] = *(const u16x8*)&Bs[(wn * 128 + nt * 16 + l15) * 40 + quad * 8];
#pragma unroll
        for (int mt = 0; mt < 4; mt++)
#pragma unroll
            for (int nt = 0; nt < 8; nt++)
                acc[mt][nt] = mfma_bf16(af[mt], bfr[nt], acc[mt][nt]);
        __syncthreads();
    }
    float bv[8];
#pragma unroll
    for (int gnt = 0; gnt < 8; ++gnt) bv[gnt] = bias[wn * 128 + gnt * 16 + l15];
#pragma unroll
    for (int mt = 0; mt < 4; ++mt)
#pragma unroll
        for (int r2 = 0; r2 < 4; ++r2) {
            const int t = t0 + wm * 64 + mt * 16 + quad * 4 + r2;
            unsigned short* dst = projsw + ((size_t)(b * Tt + t)) * Hh + l15 * 4;
#pragma unroll
            for (int wv = 0; wv < 2; ++wv) {
                u16x4 v;
#pragma unroll
                for (int nt = 0; nt < 4; ++nt)
                    v[nt] = f2bf(acc[mt][wv * 4 + nt][r2] + bv[wv * 4 + nt]);
                *(u16x4*)(dst + (wn * 2 + wv) * 64) = v;
            }
        }
}

// ---------------- recurrence + fused FC head: 1 batch per block --------------
// 256 blocks x 512 threads. Wave w owns h-cols [w*64, w*64+64), split across
// pipes: col-tiles 0-1 (quads 0-1) on MFMA (16 + 2 FC insts/wave), tiles 2-3
// (quads 2-3) on VALU sdot4. The af[j] A-fragment reads already give quad q the
// K-quarter {k8*64+q*16..+16} in registers, so the sdot4s need NO extra LDS
// traffic; quad-reduce = ds_swizzle(^16, issued early so latency hides under
// the remaining dots) + permlane32_swap(^32, VALU-cheap). Integer sums are
// bit-identical to the MFMA path. One barrier/step; warm-start own-fragment
// read crosses the barrier in flight; proj prefetched 1 step ahead.

__global__ __launch_bounds__(512, 2) void k_rnn(
        const unsigned short* __restrict__ projsw, const int* __restrict__ w1frag,
        const int* __restrict__ wfcfrag, const int* __restrict__ wvalu,
        const float* __restrict__ b_fc, const int* __restrict__ lengths,
        float* __restrict__ out) {
    const int b = blockIdx.x;
    const int tid = threadIdx.x, w = tid >> 6, lane = tid & 63;
    const int quad = lane >> 4, l15 = lane & 15;
    __shared__ __align__(16) char hbuf[2][512];
    __shared__ int fcpart[2][8][32];

    const int len = lengths[b];
    const i32x4 zz = {0, 0, 0, 0};

    // W_hh MFMA fragments (tiles 0-1), k8 permuted: slot j holds k8p=(w+j)&7
    i32x4 wf[2][8];
    int koff[8];
    {
        const i32x4* wsrc = (const i32x4*)w1frag;
#pragma unroll
        for (int j = 0; j < 8; ++j) {
            const int k8p = (w + j) & 7;
            koff[j] = k8p * 64 + quad * 16;
#pragma unroll
            for (int nt = 0; nt < 2; ++nt)
                wf[nt][j] = wsrc[((w * 4 + nt) * 8 + k8p) * 64 + lane];
        }
    }
    // W_hh sdot4 dwords (tiles 2-3), j-slot pre-permuted in prep
    i32x4 wv[2][8];
    {
        const i32x4* vsrc = (const i32x4*)wvalu;
#pragma unroll
        for (int m = 0; m < 2; ++m)
#pragma unroll
            for (int j = 0; j < 8; ++j)
                wv[m][j] = vsrc[((w * 2 + m) * 8 + j) * 64 + lane];
    }
    // FC slice: wave w handles K-slice k8=w, both n-tiles (a 0-15, 16-31)
    i32x4 wfcs[2];
    {
        const i32x4* fsrc = (const i32x4*)wfcfrag;
        wfcs[0] = fsrc[(0 * 8 + w) * 64 + lane];
        wfcs[1] = fsrc[(1 * 8 + w) * 64 + lane];
    }
    // FC reducer: wave 7, lanes 0-31 (action dim = lane)
    const bool red = (w == 7) && (lane < 32);
    const bool a_ok = red && (lane < Aa);
    const float bfc_r = a_ok ? b_fc[lane] : 0.f;
    float* const obase = out + (size_t)b * Tt * Aa + lane;

    const float C1 = 1.0f / (QW_SCALE * 127.0f);
    const int hoff = w * 64 + quad * 16 + l15;   // this lane's h column
    const int ownoff = w * 64 + quad * 16;       // own A-fragment offset (k8=w)
    const unsigned short* pp = projsw + (size_t)b * Tt * Hh + (w * 64 + l15 * 4 + quad);

    // ---- t = 0: h = tanh(proj), no recurrence ----
    i32x4 af_own;
    {
        const float hv = tanh_fast(bf2f(pp[0]));
        const int q = (int)rintf(hv * 127.0f);
        hbuf[0][hoff] = (char)q;
        asm volatile("s_waitcnt lgkmcnt(0)" ::: "memory");
        af_own = *(const i32x4*)(&hbuf[0][0] + ownoff);
        asm volatile("s_barrier" ::: "memory");
    }

    unsigned short cv = (len > 1) ? pp[Hh] : (unsigned short)0;
    for (int t = 1; t < len; ++t) {
        const unsigned short nv = pp[(size_t)((t + 1 < len) ? t + 1 : len - 1) * Hh];
        const char* rb = &hbuf[(t - 1) & 1][0];
        char* wb = &hbuf[t & 1][0];

        // wave-7: reduce FC partials of h(t-2) -> av(t-2); loads hide under compute
        int rsum = 0;
        const bool do_red = red && (t >= 2);
        if (do_red) {
            const int* fp = &fcpart[t & 1][0][0];
#pragma unroll
            for (int kw = 0; kw < 8; ++kw) rsum += fp[kw * 32 + lane];
        }

        i32x4 af[8];
        af[0] = af_own;
#pragma unroll
        for (int j = 1; j < 8; ++j) af[j] = *(const i32x4*)(rb + koff[j]);

        // MFMA pipe: tiles 0-1 + FC (own slice warm: zero post-barrier latency)
        i32x4 a0 = MFMA8(af[0], wf[0][0], zz);
        i32x4 a1 = MFMA8(af[0], wf[1][0], zz);
        i32x4 aF0 = MFMA8(af[0], wfcs[0], zz);
        i32x4 aF1 = MFMA8(af[0], wfcs[1], zz);
        // VALU pipe: tiles 2-3, two interleaved independent chains
        int v0 = 0, v1 = 0;
#pragma unroll
        for (int j = 0; j < 8; ++j) {
            if (j >= 1) {
                a0 = MFMA8(af[j], wf[0][j], a0);
                a1 = MFMA8(af[j], wf[1][j], a1);
            }
#pragma unroll
            for (int d = 0; d < 4; ++d) {
                v0 = __builtin_amdgcn_sdot4(af[j][d], wv[0][j][d], v0, false);
                v1 = __builtin_amdgcn_sdot4(af[j][d], wv[1][j][d], v1, false);
            }
        }
        // quad butterfly: ^16 (ds_swizzle, issued early) then ^32 (permlane)
        const int s0 = v0 + __builtin_amdgcn_ds_swizzle(v0, 0x401F);
        const int s1 = v1 + __builtin_amdgcn_ds_swizzle(v1, 0x401F);
        const int full0 = xor32_sum(s0);
        const int full1 = xor32_sum(s1);

        // stash FC k8=w partials of h(t-1)
        if (quad == 0) {
            fcpart[(t - 1) & 1][w][l15]      = aF0[0];
            fcpart[(t - 1) & 1][w][16 + l15] = aF1[0];
        }
        if (do_red && a_ok)
            obase[(size_t)(t - 2) * Aa] = C1 * (float)rsum + bfc_r;

        // owner select: quad0->MFMA a0, quad1->a1, quad2->full0, quad3->full1
        int sel = full1;
        sel = (quad == 2) ? full0 : sel;
        sel = (quad == 1) ? a1[0] : sel;
        sel = (quad == 0) ? a0[0] : sel;
        const float hv = tanh_fast(bf2f(cv) + C1 * (float)sel);
        const int q = (int)rintf(hv * 127.0f);
        wb[hoff] = (char)q;
        asm volatile("s_waitcnt lgkmcnt(0)" ::: "memory");   // h write visible
        af_own = *(const i32x4*)(wb + ownoff);               // pre-read own frag
        asm volatile("s_barrier" ::: "memory");              // read stays in flight
        cv = nv;
    }

    // ---- tail: FC partials of h(len-1), then reduce av(len-2), av(len-1) ----
    {
        i32x4 aF0 = MFMA8(af_own, wfcs[0], zz);
        i32x4 aF1 = MFMA8(af_own, wfcs[1], zz);
        if (quad == 0) {
            fcpart[(len - 1) & 1][w][l15]      = aF0[0];
            fcpart[(len - 1) & 1][w][16 + l15] = aF1[0];
        }
    }
    asm volatile("s_waitcnt lgkmcnt(0)\n\ts_barrier" ::: "memory");
    if (red) {
        if (len >= 2) {
            const int* fp = &fcpart[(len - 2) & 1][0][0];
            int s = 0;
#pragma unroll
            for (int kw = 0; kw < 8; ++kw) s += fp[kw * 32 + lane];
            if (a_ok) obase[(size_t)(len - 2) * Aa] = C1 * (float)s + bfc_r;
        }
        const int* fp2 = &fcpart[(len - 1) & 1][0][0];
        int s2 = 0;
#pragma unroll
        for (int kw = 0; kw < 8; ++kw) s2 += fp2[kw * 32 + lane];
        if (a_ok) obase[(size_t)(len - 1) * Aa] = C1 * (float)s2 + bfc_r;
    }
}

// ---------------- launch ----------------

extern "C" void kernel_launch(void* const* d_in, const int* in_sizes, int n_in,
                              void* d_out, int out_size, void* d_ws, size_t ws_size,
                              hipStream_t stream) {
    const float* x       = (const float*)d_in[0];
    const int*   lengths = (const int*)d_in[2];
    const float* wih     = (const float*)d_in[3];
    const float* whh     = (const float*)d_in[4];
    const float* bih     = (const float*)d_in[5];
    const float* bhh     = (const float*)d_in[6];
    const float* wfc     = (const float*)d_in[7];
    const float* bfc     = (const float*)d_in[8];
    float* out = (float*)d_out;
    char* ws = (char*)d_ws;

    const size_t OFF_PROJ  = 0;                          // B*T*H*2 = 134217728
    const size_t OFF_WIH   = OFF_PROJ + 134217728ull;    // 262144
    const size_t OFF_W1    = OFF_WIH + 262144;           // 512*512 i8 = 262144
    const size_t OFF_WFCF  = OFF_W1 + 262144;            // 2*8*64*16 = 16384
    const size_t OFF_WV    = OFF_WFCF + 16384;           // 8*2*8*64*16 = 131072
    const size_t OFF_BIAS  = OFF_WV + 131072;            // 2048

    unsigned short* projsw  = (unsigned short*)(ws + OFF_PROJ);
    unsigned short* wih_bf  = (unsigned short*)(ws + OFF_WIH);
    int*            w1frag  = (int*)(ws + OFF_W1);
    int*            wfcfrag = (int*)(ws + OFF_WFCF);
    int*            wvalu   = (int*)(ws + OFF_WV);
    float* bias             = (float*)(ws + OFF_BIAS);

    k_misc<<<1, 256, 0, stream>>>(bih, bhh, wfc, lengths, bias, wfcfrag,
                                  out + (size_t)Bb * Tt * Aa);
    k_cast_wih<<<128, 256, 0, stream>>>(wih, wih_bf);
    k_prep_whh<<<96, 256, 0, stream>>>(whh, w1frag, wvalu);
    k_prefill<<<2304, 256, 0, stream>>>(bfc, out);
    k_gemm_proj<<<1024, 512, 0, stream>>>(x, wih_bf, bias, lengths, projsw);
    k_rnn<<<Bb, 512, 0, stream>>>(projsw, w1frag, wfcfrag, wvalu, bfc,
                                  lengths, out);
}